// Round 11
// baseline (281.372 us; speedup 1.0000x reference)
//
#include <hip/hip_runtime.h>
#include <hip/hip_bf16.h>

#define BATCH 2
#define SEQ   2048
#define DIM   2048
#define NHEAD 16
#define HDIM  128

// LDS strides (elements). Multiples of 8 (16B alignment for b128); bank
// audits in comments at each access site.
#define KSTRIDE 136
#define VSTRIDE 72
#define PSTRIDE 72

typedef __bf16 bf16;
typedef __attribute__((ext_vector_type(2))) __bf16 bf16x2;
typedef __attribute__((ext_vector_type(4))) __bf16 bf16x4;
typedef __attribute__((ext_vector_type(8))) __bf16 bf16x8;
typedef __attribute__((ext_vector_type(4))) float f32x4;

// v_exp_f32: D = 2^S0 (hardware transcendental)
__device__ __forceinline__ float exp2_hw(float x) { return __builtin_amdgcn_exp2f(x); }

// ---------------------------------------------------------------------------
// Fused prep (single dispatch): cvt x -> bf16 (blocks <4096) and the two
// weight transposes (write-side paired-k b32 into padded LDS, conflict-free).
// ---------------------------------------------------------------------------
__global__ __launch_bounds__(256)
void prep_kernel(const float* __restrict__ x, bf16* __restrict__ xb,
                 const float* __restrict__ Wq, bf16* __restrict__ Wtq,
                 const float* __restrict__ Wo, bf16* __restrict__ Wto)
{
    __shared__ bf16 T[64 * 72];
    const int bid = blockIdx.x;
    if (bid < 4096) {
        const size_t i = ((size_t)bid * 256 + threadIdx.x) * 8;
        const float4 f0 = *(const float4*)(x + i);
        const float4 f1 = *(const float4*)(x + i + 4);
        *(bf16x8*)(xb + i) = (bf16x8){(bf16)f0.x, (bf16)f0.y, (bf16)f0.z, (bf16)f0.w,
                                      (bf16)f1.x, (bf16)f1.y, (bf16)f1.z, (bf16)f1.w};
        return;
    }
    int t = bid - 4096;
    const float* W  = (t < 1024) ? Wq : Wo;
    bf16*        Wt = (t < 1024) ? Wtq : Wto;
    t &= 1023;
    const int kb = (t >> 5) * 64, nb = (t & 31) * 64;

    const int a = threadIdx.x & 31;     // k-pair index
    const int g = threadIdx.x >> 5;     // n-slice 0..7
    {
        const float* s0 = W + (size_t)(kb + 2 * a) * DIM + nb + g * 8;
        const float4 r0a = *(const float4*)(s0);
        const float4 r0b = *(const float4*)(s0 + 4);
        const float4 r1a = *(const float4*)(s0 + DIM);
        const float4 r1b = *(const float4*)(s0 + DIM + 4);
        float v0[8] = {r0a.x, r0a.y, r0a.z, r0a.w, r0b.x, r0b.y, r0b.z, r0b.w};
        float v1[8] = {r1a.x, r1a.y, r1a.z, r1a.w, r1b.x, r1b.y, r1b.z, r1b.w};
        #pragma unroll
        for (int i = 0; i < 8; ++i)
            *(bf16x2*)&T[(g * 8 + i) * 72 + 2 * a] = (bf16x2){(bf16)v0[i], (bf16)v1[i]};
    }
    __syncthreads();

    const int r  = threadIdx.x >> 2;          // output n row 0..63
    const int k0 = (threadIdx.x & 3) * 16;    // k chunk
    bf16x8 o0 = *(const bf16x8*)&T[r * 72 + k0];
    bf16x8 o1 = *(const bf16x8*)&T[r * 72 + k0 + 8];
    *(bf16x8*)(Wt + (size_t)(nb + r) * DIM + kb + k0)     = o0;
    *(bf16x8*)(Wt + (size_t)(nb + r) * DIM + kb + k0 + 8) = o1;
}

// ---------------------------------------------------------------------------
// GEMM v3: C = A @ Bt^T, bf16. Register-prefetch + ping-pong LDS pipeline
// (attn-proven pattern): tile k+1 sits in VGPRs during compute on tile k,
// commits to the other LDS buffer at iteration top -> ONE barrier/iter and
// no exposed global latency between barriers (vs global_load_lds + vmcnt(0)
// drain = the m97 structural stall). Half-buffers [2][128*32] keep the
// verified m97 bank layout; ds_writes are lane-contiguous b128 (conflict-
// free). LDS 64 KB -> 2 blocks/CU; VGPR ~110 (acc 64 + prefetch 32).
// ---------------------------------------------------------------------------
template<bool OUT_F32_BIAS>
__global__ __launch_bounds__(256)
void gemm_bt(const bf16* __restrict__ A, const bf16* __restrict__ Bt,
             const float* __restrict__ bias, void* __restrict__ Cptr,
             int M, int N, int K)
{
    __shared__ bf16 As[2][2][128 * 32];   // [buf][k-half][row*32]
    __shared__ bf16 Bs[2][2][128 * 32];

    const int tid  = threadIdx.x;
    const int wave = tid >> 6;
    const int lane = tid & 63;
    const int quad = lane >> 4;
    const int l16  = lane & 15;
    const int wr   = (wave >> 1) * 64;
    const int wc   = (wave & 1) * 64;
    const int rowBase = blockIdx.y * 128;
    const int colBase = blockIdx.x * 128;

    // staging map: thread covers (rh,kh) 16B chunks; LDS addr = base +
    // (rh*64 + wave*16 + (lane>>2))*32 + (lane&3)*8 -> lane-contiguous 16B.
    const int srow = lane >> 2;
    const int scol = (lane & 3) * 8;
    const int ldsOff = (wave * 16 + srow) * 32 + scol;
    const bf16* aBase = A  + (size_t)(rowBase + wave * 16 + srow) * K + scol;
    const bf16* bBase = Bt + (size_t)(colBase + wave * 16 + srow) * K + scol;

    f32x4 acc[4][4] = {};
    bf16x8 pa[2][2], pb[2][2];   // prefetch regs [rh][kh]

    // prologue: tile0 -> regs -> buf0; tile1 -> regs
    #pragma unroll
    for (int rh = 0; rh < 2; ++rh)
        #pragma unroll
        for (int kh = 0; kh < 2; ++kh) {
            pa[rh][kh] = *(const bf16x8*)(aBase + (size_t)rh * 64 * K + kh * 32);
            pb[rh][kh] = *(const bf16x8*)(bBase + (size_t)rh * 64 * K + kh * 32);
        }
    #pragma unroll
    for (int rh = 0; rh < 2; ++rh)
        #pragma unroll
        for (int kh = 0; kh < 2; ++kh) {
            *(bf16x8*)&As[0][kh][rh * 2048 + ldsOff] = pa[rh][kh];
            *(bf16x8*)&Bs[0][kh][rh * 2048 + ldsOff] = pb[rh][kh];
        }
    #pragma unroll
    for (int rh = 0; rh < 2; ++rh)
        #pragma unroll
        for (int kh = 0; kh < 2; ++kh) {
            pa[rh][kh] = *(const bf16x8*)(aBase + (size_t)rh * 64 * K + 64 + kh * 32);
            pb[rh][kh] = *(const bf16x8*)(bBase + (size_t)rh * 64 * K + 64 + kh * 32);
        }
    __syncthreads();

    for (int k0 = 0; k0 < K; k0 += 64) {
        const int buf = (k0 >> 6) & 1;

        // commit prefetched tile (k0+64) to the other buffer
        if (k0 + 64 < K) {
            #pragma unroll
            for (int rh = 0; rh < 2; ++rh)
                #pragma unroll
                for (int kh = 0; kh < 2; ++kh) {
                    *(bf16x8*)&As[buf ^ 1][kh][rh * 2048 + ldsOff] = pa[rh][kh];
                    *(bf16x8*)&Bs[buf ^ 1][kh][rh * 2048 + ldsOff] = pb[rh][kh];
                }
        }
        // prefetch tile (k0+128) into regs (lands during this + next compute)
        if (k0 + 128 < K) {
            #pragma unroll
            for (int rh = 0; rh < 2; ++rh)
                #pragma unroll
                for (int kh = 0; kh < 2; ++kh) {
                    pa[rh][kh] = *(const bf16x8*)(aBase + (size_t)rh * 64 * K + k0 + 128 + kh * 32);
                    pb[rh][kh] = *(const bf16x8*)(bBase + (size_t)rh * 64 * K + k0 + 128 + kh * 32);
                }
        }

        // compute on buf (tile k0)
        #pragma unroll
        for (int ks = 0; ks < 2; ++ks) {
            bf16x8 a[4], b[4];
            #pragma unroll
            for (int i = 0; i < 4; ++i)
                a[i] = *(const bf16x8*)&As[buf][ks][(wr + i * 16 + l16) * 32 + quad * 8];
            #pragma unroll
            for (int j = 0; j < 4; ++j)
                b[j] = *(const bf16x8*)&Bs[buf][ks][(wc + j * 16 + l16) * 32 + quad * 8];
            #pragma unroll
            for (int i = 0; i < 4; ++i)
                #pragma unroll
                for (int j = 0; j < 4; ++j)
                    acc[i][j] = __builtin_amdgcn_mfma_f32_16x16x32_bf16(a[i], b[j], acc[i][j], 0, 0, 0);
        }
        __syncthreads();   // single barrier: readers of buf done, writers of buf^1 done
    }

    #pragma unroll
    for (int i = 0; i < 4; ++i) {
        #pragma unroll
        for (int j = 0; j < 4; ++j) {
            #pragma unroll
            for (int r = 0; r < 4; ++r) {
                const int row = rowBase + wr + i * 16 + quad * 4 + r;
                const int col = colBase + wc + j * 16 + l16;
                const float v = acc[i][j][r];
                if (OUT_F32_BIAS) ((float*)Cptr)[(size_t)row * N + col] = v + bias[col];
                else              ((bf16*)Cptr)[(size_t)row * N + col] = (bf16)v;
            }
        }
    }
}

// ---------------------------------------------------------------------------
// Attention (unchanged from round 10): S^T-form, q-tile 128, 4 waves x 32
// q-rows, 2 blocks/CU, register prefetch of next K/V tile, XCD swizzle
// (FETCH 72->8 MB verified; kernel is LDS/MFMA-bound at ~95 us).
// ---------------------------------------------------------------------------
__global__ __launch_bounds__(256, 2)
void attn_kernel(const bf16* __restrict__ q, bf16* __restrict__ y)
{
    __shared__ bf16 Ks[64 * KSTRIDE];     // 17408 B  [kv][hd]
    __shared__ bf16 Vt[HDIM * VSTRIDE];   // 18432 B  [hd][kv]
    __shared__ bf16 Ps[128 * PSTRIDE];    // 18432 B  [q][kv]

    const int tid  = threadIdx.x;
    const int wave = tid >> 6;     // 0..3
    const int lane = tid & 63;
    const int quad = lane >> 4;
    const int l16  = lane & 15;

    // XCD swizzle: all 16 q-tiles of a (b,h) on one XCD.
    const int p   = blockIdx.x;
    const int xcd = p & 7;
    const int pos = p >> 3;
    const int g   = xcd * 4 + (pos & 3);   // (b,h) group 0..31
    const int qt  = pos >> 2;              // 0..15
    const int h   = g & 15;
    const int bb  = g >> 4;

    const bf16* qb = q + (size_t)bb * SEQ * DIM + (size_t)h * HDIM;

    // Q fragments -> registers (wave owns q rows [wave*32, wave*32+32)).
    const float qs = 0.12752820031096662f;   // (1/sqrt(128)) * log2(e)
    bf16x8 aq[2][4];
    #pragma unroll
    for (int nt = 0; nt < 2; ++nt) {
        #pragma unroll
        for (int ks = 0; ks < 4; ++ks) {
            const bf16* src = qb + (size_t)(qt * 128 + wave * 32 + nt * 16 + l16) * DIM + ks * 32 + quad * 8;
            bf16x8 v = *(const bf16x8*)src;
            bf16x8 o;
            #pragma unroll
            for (int e = 0; e < 8; ++e) o[e] = (bf16)((float)v[e] * qs);
            aq[nt][ks] = o;
        }
    }

    float lpart[2] = {0.f, 0.f};
    f32x4 yacc[2][8] = {};

    // staging index maps (both conflict-free, round-6 audit)
    const int kr   = tid >> 2;         // kv row 0..63 (Ks path)
    const int koff = (tid & 3) * 32;
    const int sp   = tid & 31;         // kv pair (Vt path)
    const int ss   = tid >> 5;         // hd slice of 16

    const bf16* srcK = qb + (size_t)kr * DIM + koff;
    const bf16* srcV = qb + (size_t)(2 * sp) * DIM + ss * 16;

    // prologue: prefetch tile 0 into registers
    bf16x8 kreg[4], va[2], vb[2];
    #pragma unroll
    for (int c = 0; c < 4; ++c) kreg[c] = *(const bf16x8*)(srcK + c * 8);
    va[0] = *(const bf16x8*)(srcV + 0);
    va[1] = *(const bf16x8*)(srcV + 8);
    vb[0] = *(const bf16x8*)(srcV + DIM + 0);
    vb[1] = *(const bf16x8*)(srcV + DIM + 8);

    for (int kt = 0; kt < SEQ / 64; ++kt) {
        __syncthreads();   // prev iteration done reading Ks/Vt

        // commit prefetched tile to LDS
        #pragma unroll
        for (int c = 0; c < 4; ++c)
            *(bf16x8*)&Ks[kr * KSTRIDE + koff + c * 8] = kreg[c];
        #pragma unroll
        for (int c = 0; c < 2; ++c)
            #pragma unroll
            for (int e = 0; e < 8; ++e)
                *(bf16x2*)&Vt[(ss * 16 + c * 8 + e) * VSTRIDE + 2 * sp] = (bf16x2){va[c][e], vb[c][e]};

        // prefetch NEXT tile (overlaps the compute phase below)
        if (kt + 1 < SEQ / 64) {
            const bf16* nK = srcK + (size_t)(kt + 1) * 64 * DIM;
            const bf16* nV = srcV + (size_t)(kt + 1) * 64 * DIM;
            #pragma unroll
            for (int c = 0; c < 4; ++c) kreg[c] = *(const bf16x8*)(nK + c * 8);
            va[0] = *(const bf16x8*)(nV + 0);
            va[1] = *(const bf16x8*)(nV + 8);
            vb[0] = *(const bf16x8*)(nV + DIM + 0);
            vb[1] = *(const bf16x8*)(nV + DIM + 8);
        }
        __syncthreads();

        // S^T phase per 16-kv strip (mt): MFMA(A=Ks-frag, B=aq).
        // C-layout of S^T: kv = mt*16 + quad*4 + r, q = wave*32 + nt*16 + l16.
        #pragma unroll
        for (int mt = 0; mt < 4; ++mt) {
            bf16x8 ak[4];
            #pragma unroll
            for (int ks = 0; ks < 4; ++ks)
                ak[ks] = *(const bf16x8*)&Ks[(mt * 16 + l16) * KSTRIDE + ks * 32 + quad * 8];
            f32x4 s[2] = {};
            #pragma unroll
            for (int ks = 0; ks < 4; ++ks)
                #pragma unroll
                for (int nt = 0; nt < 2; ++nt)
                    s[nt] = __builtin_amdgcn_mfma_f32_16x16x32_bf16(ak[ks], aq[nt][ks], s[nt], 0, 0, 0);
            #pragma unroll
            for (int nt = 0; nt < 2; ++nt) {
                float p0 = exp2_hw(s[nt][0]);
                float p1 = exp2_hw(s[nt][1]);
                float p2 = exp2_hw(s[nt][2]);
                float p3 = exp2_hw(s[nt][3]);
                lpart[nt] += (p0 + p1) + (p2 + p3);
                *(bf16x4*)&Ps[(wave * 32 + nt * 16 + l16) * PSTRIDE + mt * 16 + quad * 4] =
                    (bf16x4){(bf16)p0, (bf16)p1, (bf16)p2, (bf16)p3};
            }
        }

        // PV: Y += P @ V. A = own-wave P rows (in-wave LDS dep only), B = V^T.
        #pragma unroll
        for (int ks2 = 0; ks2 < 2; ++ks2) {
            bf16x8 ap[2];
            #pragma unroll
            for (int i = 0; i < 2; ++i)
                ap[i] = *(const bf16x8*)&Ps[(wave * 32 + i * 16 + l16) * PSTRIDE + ks2 * 32 + quad * 8];
            #pragma unroll
            for (int n = 0; n < 8; ++n) {
                bf16x8 bv = *(const bf16x8*)&Vt[(n * 16 + l16) * VSTRIDE + ks2 * 32 + quad * 8];
                #pragma unroll
                for (int i = 0; i < 2; ++i)
                    yacc[i][n] = __builtin_amdgcn_mfma_f32_16x16x32_bf16(ap[i], bv, yacc[i][n], 0, 0, 0);
            }
        }
    }

    // denominators: reduce per-lane partials across the 4 quad-lanes per q.
    float lfull[2];
    #pragma unroll
    for (int nt = 0; nt < 2; ++nt) {
        float l = lpart[nt];
        l += __shfl_xor(l, 16);
        l += __shfl_xor(l, 32);
        lfull[nt] = l;
    }

    bf16* yb = y + (size_t)bb * SEQ * DIM + (size_t)(qt * 128) * DIM + (size_t)h * HDIM;
    #pragma unroll
    for (int i = 0; i < 2; ++i) {
        #pragma unroll
        for (int r = 0; r < 4; ++r) {
            const float lv  = __shfl(lfull[i], (lane & 48) | (quad * 4 + r));
            const float inv = 1.f / lv;
            const int row = wave * 32 + i * 16 + quad * 4 + r;
            #pragma unroll
            for (int n = 0; n < 8; ++n)
                yb[(size_t)row * DIM + n * 16 + l16] = (bf16)(yacc[i][n][r] * inv);
        }
    }
}

// ---------------------------------------------------------------------------
// Workspace layout (41.94 MB, unchanged):
//   ws[0 .. N)     qws ; ws[N .. 2N) yws (first half doubles as Wtq) ;
//   ws[2N .. )     Wto ; d_out[0 .. N) xb (dead before gemm2 writes d_out)
// ---------------------------------------------------------------------------
extern "C" void kernel_launch(void* const* d_in, const int* in_sizes, int n_in,
                              void* d_out, int out_size, void* d_ws, size_t ws_size,
                              hipStream_t stream)
{
    const float* x  = (const float*)d_in[0];
    const float* Wq = (const float*)d_in[1];
    const float* Wo = (const float*)d_in[2];
    const float* bo = (const float*)d_in[3];

    const size_t NELEM = (size_t)BATCH * SEQ * DIM;
    bf16* qws = (bf16*)d_ws;
    bf16* yws = qws + NELEM;
    bf16* Wtq = yws;                 // aliased: gemm1 reads before attn clobbers
    bf16* Wto = qws + 2 * NELEM;
    bf16* xb  = (bf16*)d_out;        // scratch inside d_out, dead by gemm2

    const int M = BATCH * SEQ;
    dim3 gg(DIM / 128, M / 128);

    prep_kernel<<<6144, 256, 0, stream>>>(x, xb, Wq, Wtq, Wo, Wto);
    gemm_bt<false><<<gg, 256, 0, stream>>>(xb, Wtq, nullptr, qws, M, DIM, DIM);
    attn_kernel<<<512, 256, 0, stream>>>(qws, yws);
    gemm_bt<true><<<gg, 256, 0, stream>>>(yws, Wto, bo, (float*)d_out, M, DIM, DIM);
}